// Round 2
// baseline (435.193 us; speedup 1.0000x reference)
//
#include <hip/hip_runtime.h>

typedef unsigned int UI;
typedef unsigned short u16;

typedef short short8 __attribute__((ext_vector_type(8)));
typedef float floatx16 __attribute__((ext_vector_type(16)));
typedef unsigned short ushort8 __attribute__((ext_vector_type(8)));

__device__ __forceinline__ float bf2f(u16 u) {
  return __uint_as_float(((UI)u) << 16);
}
__device__ __forceinline__ u16 f2bf(float x) {  // RNE
  UI u = __float_as_uint(x);
  u += 0x7fffu + ((u >> 16) & 1u);
  return (u16)(u >> 16);
}
__device__ __forceinline__ float fsigmoid(float v) {
  float e = __builtin_amdgcn_exp2f(-1.44269504089f * v);
  return __builtin_amdgcn_rcpf(1.0f + e);
}
__device__ __forceinline__ float fsilu(float v) { return v * fsigmoid(v); }

// ---------------- K1: layernorm h (128) and x (3) ----------------
__global__ __launch_bounds__(256) void k1_ln(
    const float* __restrict__ h, const float* __restrict__ x,
    const float* __restrict__ lnh_w, const float* __restrict__ lnh_b,
    const float* __restrict__ lnx_w, const float* __restrict__ lnx_b,
    float* __restrict__ hln, float* __restrict__ xln) {
  const int wv = threadIdx.x >> 6, lane = threadIdx.x & 63;
#pragma unroll 1
  for (int s = 0; s < 2; ++s) {
    const int n = blockIdx.x * 8 + wv * 2 + s;  // 128 blocks * 8 nodes
    const float* hp = h + n * 128;
    float v0 = hp[lane], v1 = hp[lane + 64];
    float sum = v0 + v1;
#pragma unroll
    for (int m = 1; m < 64; m <<= 1) sum += __shfl_xor(sum, m);
    float mean = sum * 0.0078125f;
    float d0 = v0 - mean, d1 = v1 - mean;
    float vs = d0 * d0 + d1 * d1;
#pragma unroll
    for (int m = 1; m < 64; m <<= 1) vs += __shfl_xor(vs, m);
    float rstd = __builtin_amdgcn_rcpf(__builtin_amdgcn_sqrtf(vs * 0.0078125f + 1e-5f));
    hln[n * 128 + lane]      = d0 * rstd * lnh_w[lane] + lnh_b[lane];
    hln[n * 128 + lane + 64] = d1 * rstd * lnh_w[lane + 64] + lnh_b[lane + 64];
    if (lane == 0) {
      float a = x[n * 3], b2 = x[n * 3 + 1], c = x[n * 3 + 2];
      float m3 = (a + b2 + c) * (1.f / 3.f);
      float va = (a - m3) * (a - m3) + (b2 - m3) * (b2 - m3) + (c - m3) * (c - m3);
      float rs = __builtin_amdgcn_rcpf(__builtin_amdgcn_sqrtf(va * (1.f / 3.f) + 1e-5f));
      xln[n * 3 + 0] = (a - m3) * rs * lnx_w[0] + lnx_b[0];
      xln[n * 3 + 1] = (b2 - m3) * rs * lnx_w[1] + lnx_b[1];
      xln[n * 3 + 2] = (c - m3) * rs * lnx_w[2] + lnx_b[2];
    }
  }
}

// ---------------- K2: per-node pre-GEMMs + weight repacks ----------------
__global__ __launch_bounds__(256, 2) void k2_pre(
    const float* __restrict__ hln,
    const float* __restrict__ edg1_w, const float* __restrict__ edg1_b,
    const float* __restrict__ cor1_w, const float* __restrict__ cor1_b,
    const float* __restrict__ edg2_w, const float* __restrict__ cor2_w,
    u16* __restrict__ peA, u16* __restrict__ peB,
    u16* __restrict__ pcA, u16* __restrict__ pcB,
    u16* __restrict__ w2e, u16* __restrict__ w2c,
    float* __restrict__ wdwr) {
  const int tid = threadIdx.x;
  const int bx = blockIdx.x;
  if (bx >= 256) {
    const float* src = (bx == 256) ? edg2_w : cor2_w;
    u16* dst = (bx == 256) ? w2e : w2c;
    for (int idx = tid; idx < 16384; idx += 256) {
      int f = idx >> 7, k = idx & 127;
      dst[f * 136 + k] = f2bf(src[idx]);
    }
    const float* w1 = (bx == 256) ? edg1_w : cor1_w;
    float* wvv = wdwr + ((bx == 256) ? 0 : 256);
    if (tid < 128) wvv[tid] = w1[tid * 258 + 256];           // wd (dsq col)
    else           wvv[tid] = w1[(tid - 128) * 258 + 257];   // wr (r0 col)
    return;
  }
  __shared__ __align__(16) float hl[16][132];
  const int arr = bx >> 6;
  const int nb = bx & 63;
  const int n0 = nb * 16;
  for (int idx = tid; idx < 2048; idx += 256) {
    int r = idx >> 7, k = idx & 127;
    hl[r][k] = hln[(n0 + r) * 128 + k];
  }
  __syncthreads();
  const int f = tid & 127, nh = tid >> 7;
  const float* w1 = (arr < 2) ? edg1_w : cor1_w;
  const int off = (arr & 1) ? 128 : 0;
  u16* dst = (arr == 0) ? peA : (arr == 1) ? peB : (arr == 2) ? pcA : pcB;
  float bias = 0.f;
  if (arr == 0) bias = edg1_b[f];
  if (arr == 2) bias = cor1_b[f];
  const float* wrow = w1 + f * 258 + off;
  float2 wreg[64];
#pragma unroll
  for (int t = 0; t < 64; ++t) wreg[t] = *(const float2*)(wrow + t * 2);
#pragma unroll 1
  for (int s = 0; s < 8; ++s) {
    int nl = nh * 8 + s;
    float acc = bias;
#pragma unroll
    for (int t = 0; t < 64; ++t) {
      float2 iv = *(const float2*)&hl[nl][t * 2];
      acc += wreg[t].x * iv.x + wreg[t].y * iv.y;
    }
    dst[(n0 + nl) * 128 + f] = f2bf(acc);
  }
}

// ---------------- K3: fused per-pair edge/coord MLPs ----------------
// grid 1024: path = bx>>9 (0=edge,1=cor); per wg: 16 i's x 32 j's.
// wave w: j in [w*8, w*8+8); 4 passes, ONE 32x32 m-tile (16i x 2j) each.
// Live accumulators per pass: acc[4] floatx16 = 64 regs (vs 128 in the
// round-1 version, which spilled 851 MB of scratch per dispatch).
__global__ __launch_bounds__(256, 2) void k3_pair(
    const float* __restrict__ x, const float* __restrict__ x0,
    const u16* __restrict__ peA, const u16* __restrict__ peB,
    const u16* __restrict__ pcA, const u16* __restrict__ pcB,
    const u16* __restrict__ w2e, const u16* __restrict__ w2c,
    const float* __restrict__ wdwr,
    const float* __restrict__ b2e, const float* __restrict__ b2c,
    const float* __restrict__ edgi_w, const float* __restrict__ edgi_b,
    const float* __restrict__ cor3_w, const float* __restrict__ cor3_b,
    float* __restrict__ cw_t, float* __restrict__ partial) {
  __shared__ __align__(16) u16 sW[128 * 136];   // 34816 B, B-operand weights
  __shared__ __align__(16) u16 sA[16 * 136];    // pre_i rows (bf16)
  __shared__ __align__(16) u16 sB[32 * 136];    // pre_j rows (bf16)
  __shared__ __align__(16) float swd[128];
  __shared__ __align__(16) float swr[128];
  __shared__ float sxi[16][4], sxj[32][4], sx0i[16][4], sx0j[32][4];
  __shared__ __align__(16) float sagg[16][128]; // 8192 B

  const int tid = threadIdx.x;
  const int bx = blockIdx.x;
  const int path = bx >> 9;
  const int rem = bx & 511;
  const int b = rem >> 7;
  const int ib = (rem >> 3) & 15;
  const int jc = rem & 7;
  const int i0 = ib * 16, j0 = jc * 32;

  const u16* pA = path ? pcA : peA;
  const u16* pB = path ? pcB : peB;
  const u16* w2 = path ? w2c : w2e;
  const float* wdp = wdwr + path * 256;
  const float* b2 = path ? b2c : b2e;
  const float* w3 = path ? cor3_w : edgi_w;
  const float w3b = path ? cor3_b[0] : edgi_b[0];

  {
    const uint4* src = (const uint4*)w2;
    uint4* dst = (uint4*)sW;
    for (int d = tid; d < 2176; d += 256) dst[d] = src[d];
    const UI* sa_src = (const UI*)(pA + (b * 256 + i0) * 128);
    UI* sa_dst = (UI*)sA;
    for (int d = tid; d < 1024; d += 256) {
      int r = d >> 6, c = d & 63;
      sa_dst[r * 68 + c] = sa_src[d];
    }
    const UI* sb_src = (const UI*)(pB + (b * 256 + j0) * 128);
    UI* sb_dst = (UI*)sB;
    for (int d = tid; d < 2048; d += 256) {
      int r = d >> 6, c = d & 63;
      sb_dst[r * 68 + c] = sb_src[d];
    }
    if (tid < 128) swd[tid] = wdp[tid];
    else           swr[tid - 128] = wdp[tid];
    if (tid < 64) {
      int r = tid >> 2, d = tid & 3;
      sxi[r][d]  = (d < 3) ? x[(b * 256 + i0 + r) * 3 + d] : 0.f;
      sx0i[r][d] = (d < 3) ? x0[(b * 256 + i0 + r) * 3 + d] : 0.f;
    }
    if (tid < 128) {
      int r = tid >> 2, d = tid & 3;
      sxj[r][d]  = (d < 3) ? x[(b * 256 + j0 + r) * 3 + d] : 0.f;
      sx0j[r][d] = (d < 3) ? x0[(b * 256 + j0 + r) * 3 + d] : 0.f;
    }
    float* ag = (float*)sagg;
    for (int d = tid; d < 2048; d += 256) ag[d] = 0.f;
  }
  __syncthreads();

  const int lane = tid & 63;
  const int w = tid >> 6;
  const int h = lane >> 5;        // half-wave -> k-chunk of A/B frags
  const int c32 = lane & 31;      // MFMA m / n / col index
  const int il = c32 & 15;        // i within block (A m-row low bits)
  const int jh = (c32 >> 4) & 1;  // j lsb within m-tile

  const float wv0 = w3[c32], wv1 = w3[32 + c32], wv2 = w3[64 + c32], wv3 = w3[96 + c32];
  const float bv0 = b2[c32], bv1 = b2[32 + c32], bv2 = b2[64 + c32], bv3 = b2[96 + c32];

  float aggv[4][8];
#pragma unroll
  for (int a = 0; a < 4; ++a)
#pragma unroll
    for (int r = 0; r < 8; ++r) aggv[a][r] = 0.f;

#pragma unroll 1
  for (int g = 0; g < 4; ++g) {
    const int jl = w * 8 + g * 2 + jh;  // this lane's j within the m-tile
    float d0 = sxi[il][0] - sxj[jl][0];
    float d1 = sxi[il][1] - sxj[jl][1];
    float d2 = sxi[il][2] - sxj[jl][2];
    const float dsq = d0 * d0 + d1 * d1 + d2 * d2;
    float e0 = sx0i[il][0] - sx0j[jl][0];
    float e1 = sx0i[il][1] - sx0j[jl][1];
    float e2 = sx0i[il][2] - sx0j[jl][2];
    float q = e0 * e0 + e1 * e1 + e2 * e2;
    const float r0 = (q > 0.f) ? __builtin_amdgcn_sqrtf(q) : 0.f;

    floatx16 acc[4];
#pragma unroll
    for (int nt = 0; nt < 4; ++nt)
#pragma unroll
      for (int r = 0; r < 16; ++r) acc[nt][r] = 0.f;

    for (int ks = 0; ks < 8; ++ks) {
      const int f0 = ks * 16 + h * 8;
      union { float4 v[2]; float a[8]; } wd8, wr8;
      wd8.v[0] = *(const float4*)&swd[f0];
      wd8.v[1] = *(const float4*)&swd[f0 + 4];
      wr8.v[0] = *(const float4*)&swr[f0];
      wr8.v[1] = *(const float4*)&swr[f0 + 4];
      ushort8 a8 = *(const ushort8*)&sA[il * 136 + f0];
      ushort8 b8 = *(const ushort8*)&sB[jl * 136 + f0];
      short8 af;
#pragma unroll
      for (int e = 0; e < 8; ++e) {
        float xv = bf2f((u16)a8[e]) + bf2f((u16)b8[e]) +
                   dsq * wd8.a[e] + r0 * wr8.a[e];
        af[e] = (short)f2bf(fsilu(xv));
      }
#pragma unroll
      for (int nt = 0; nt < 4; ++nt) {
        short8 bfr = *(const short8*)&sW[(nt * 32 + c32) * 136 + f0];
        acc[nt] = __builtin_amdgcn_mfma_f32_32x32x16_bf16(af, bfr, acc[nt], 0, 0, 0);
      }
    }
    // epilogue: silu+bias, inner-product with w3, butterfly row-reduce
    float p[16];
#pragma unroll
    for (int r = 0; r < 16; ++r) {
      float s0 = fsilu(acc[0][r] + bv0); acc[0][r] = s0;
      float s1 = fsilu(acc[1][r] + bv1); acc[1][r] = s1;
      float s2 = fsilu(acc[2][r] + bv2); acc[2][r] = s2;
      float s3 = fsilu(acc[3][r] + bv3); acc[3][r] = s3;
      p[r] = s0 * wv0 + s1 * wv1 + s2 * wv2 + s3 * wv3;
    }
#pragma unroll
    for (int m = 1; m < 32; m <<= 1) {
#pragma unroll
      for (int r = 0; r < 16; ++r) p[r] += __shfl_xor(p[r], m);
    }
    if (path == 0) {
      float ev[16];
#pragma unroll
      for (int r = 0; r < 16; ++r) {
        int rb = (r & 3) + 8 * (r >> 2) + 4 * h;  // C/D row
        int ig = i0 + (rb & 15);
        int jg = j0 + w * 8 + g * 2 + (rb >> 4);
        float e = fsigmoid(p[r] + w3b);
        ev[r] = (ig == jg) ? 0.f : e;
      }
#pragma unroll
      for (int r = 0; r < 16; ++r) {
        int ra = (r & 3) + 4 * ((r >> 2) & 1);
        aggv[0][ra] += ev[r] * acc[0][r];
        aggv[1][ra] += ev[r] * acc[1][r];
        aggv[2][ra] += ev[r] * acc[2][r];
        aggv[3][ra] += ev[r] * acc[3][r];
      }
    } else {
      if (c32 < 16) {
        int r = c32;
        int rb = (r & 3) + 8 * (r >> 2) + 4 * h;
        int ig = i0 + (rb & 15);
        int jg = j0 + w * 8 + g * 2 + (rb >> 4);
        cw_t[(b * 256 + jg) * 256 + ig] = p[r] + w3b;
      }
    }
  }
  if (path == 0) {
#pragma unroll
    for (int nt = 0; nt < 4; ++nt)
#pragma unroll
      for (int ra = 0; ra < 8; ++ra) {
        int iloc = (ra & 3) + 4 * h + 8 * (ra >> 2);
        atomicAdd(&sagg[iloc][nt * 32 + c32], aggv[nt][ra]);
      }
    __syncthreads();
    float* dst = partial + ((b * 16 + ib) * 8 + jc) * 2048;
    const float* ag = (const float*)sagg;
    for (int d = tid; d < 2048; d += 256) dst[d] = ag[d];
  }
}

// ---------------- K4: node MLP + residual ----------------
__global__ __launch_bounds__(256, 2) void k4_node(
    const float* __restrict__ hln, const float* __restrict__ partial,
    const float* __restrict__ n1w, const float* __restrict__ n1b,
    const float* __restrict__ n2w, const float* __restrict__ n2b,
    float* __restrict__ out) {
  __shared__ __align__(16) float sin_[4][260];
  __shared__ __align__(16) float snu[4][132];
  const int tid = threadIdx.x;
  const int n0 = blockIdx.x * 4;
  for (int idx = tid; idx < 512; idx += 256) {
    int s = idx >> 7, k = idx & 127;
    sin_[s][k] = hln[(n0 + s) * 128 + k];
  }
  for (int idx = tid; idx < 512; idx += 256) {
    int s = idx >> 7, f = idx & 127;
    int n = n0 + s, b = n >> 8, i = n & 255;
    const float* pp = partial + ((b * 16 + (i >> 4)) * 8) * 2048 + (i & 15) * 128 + f;
    float a = 0.f;
#pragma unroll
    for (int j = 0; j < 8; ++j) a += pp[j * 2048];
    sin_[s][128 + f] = a;
  }
  __syncthreads();
  const int f = tid & 127, sh = tid >> 7;
  UI w1r[128];
#pragma unroll
  for (int t = 0; t < 128; ++t) {
    float2 wv = *(const float2*)(n1w + f * 256 + t * 2);
    w1r[t] = (UI)f2bf(wv.x) | ((UI)f2bf(wv.y) << 16);
  }
#pragma unroll 1
  for (int t2 = 0; t2 < 2; ++t2) {
    int s = sh * 2 + t2;
    float acc = n1b[f];
#pragma unroll
    for (int t = 0; t < 128; ++t) {
      UI wp = w1r[t];
      float2 iv = *(const float2*)&sin_[s][t * 2];
      acc += iv.x * bf2f((u16)(wp & 0xffffu)) + iv.y * bf2f((u16)(wp >> 16));
    }
    snu[s][f] = fsilu(acc);
  }
  __syncthreads();
  UI w2r[64];
#pragma unroll
  for (int t = 0; t < 64; ++t) {
    float2 wv = *(const float2*)(n2w + f * 128 + t * 2);
    w2r[t] = (UI)f2bf(wv.x) | ((UI)f2bf(wv.y) << 16);
  }
#pragma unroll 1
  for (int t2 = 0; t2 < 2; ++t2) {
    int s = sh * 2 + t2;
    float acc = n2b[f];
#pragma unroll
    for (int t = 0; t < 64; ++t) {
      UI wp = w2r[t];
      float2 iv = *(const float2*)&snu[s][t * 2];
      acc += iv.x * bf2f((u16)(wp & 0xffffu)) + iv.y * bf2f((u16)(wp >> 16));
    }
    out[3072 + (n0 + s) * 128 + f] = sin_[s][f] + acc;  // h_ln + node2(nu)
  }
}

// ---------------- K5: coordinate update ----------------
__global__ __launch_bounds__(256) void k5_x(
    const float* __restrict__ x, const float* __restrict__ xln,
    const float* __restrict__ cw_t, float* __restrict__ out) {
  const int wv = threadIdx.x >> 6, lane = threadIdx.x & 63;
  const int n = blockIdx.x * 4 + wv;
  const int b = n >> 8, i = n & 255;
  const float xi0 = x[n * 3 + 0], xi1 = x[n * 3 + 1], xi2 = x[n * 3 + 2];
  float s0 = 0.f, s1 = 0.f, s2 = 0.f;
#pragma unroll
  for (int t = 0; t < 4; ++t) {
    int j = t * 64 + lane;
    const float* xj = x + (b * 256 + j) * 3;
    float d0 = xi0 - xj[0], d1 = xi1 - xj[1], d2 = xi2 - xj[2];
    float q = d0 * d0 + d1 * d1 + d2 * d2;
    float r = (q > 0.f) ? __builtin_amdgcn_sqrtf(q) : 0.f;
    float cw = cw_t[(b * 256 + j) * 256 + i];
    float sc = cw * __builtin_amdgcn_rcpf(r + 1.f);
    s0 += sc * d0; s1 += sc * d1; s2 += sc * d2;
  }
#pragma unroll
  for (int m = 1; m < 64; m <<= 1) {
    s0 += __shfl_xor(s0, m);
    s1 += __shfl_xor(s1, m);
    s2 += __shfl_xor(s2, m);
  }
  if (lane == 0) {
    out[n * 3 + 0] = xln[n * 3 + 0] + s0;
    out[n * 3 + 1] = xln[n * 3 + 1] + s1;
    out[n * 3 + 2] = xln[n * 3 + 2] + s2;
  }
}

extern "C" void kernel_launch(void* const* d_in, const int* in_sizes, int n_in,
                              void* d_out, int out_size, void* d_ws, size_t ws_size,
                              hipStream_t stream) {
  (void)in_sizes; (void)n_in; (void)out_size; (void)ws_size;
  const float* x      = (const float*)d_in[0];
  const float* h      = (const float*)d_in[1];
  const float* x0     = (const float*)d_in[2];
  const float* lnh_w  = (const float*)d_in[3];
  const float* lnh_b  = (const float*)d_in[4];
  const float* lnx_w  = (const float*)d_in[5];
  const float* lnx_b  = (const float*)d_in[6];
  const float* edg1_w = (const float*)d_in[7];
  const float* edg1_b = (const float*)d_in[8];
  const float* edg2_w = (const float*)d_in[9];
  const float* edg2_b = (const float*)d_in[10];
  const float* edgi_w = (const float*)d_in[11];
  const float* edgi_b = (const float*)d_in[12];
  const float* node1_w= (const float*)d_in[13];
  const float* node1_b= (const float*)d_in[14];
  const float* node2_w= (const float*)d_in[15];
  const float* node2_b= (const float*)d_in[16];
  const float* cor1_w = (const float*)d_in[17];
  const float* cor1_b = (const float*)d_in[18];
  const float* cor2_w = (const float*)d_in[19];
  const float* cor2_b = (const float*)d_in[20];
  const float* cor3_w = (const float*)d_in[21];
  const float* cor3_b = (const float*)d_in[22];

  char* ws = (char*)d_ws;
  float* hln  = (float*)(ws);                 // 1024*128 f32 = 512 KB
  float* xln  = (float*)(ws + 524288);        // 1024*3 f32
  u16* peA    = (u16*)(ws + 536576);          // [1024][128] bf16
  u16* peB    = (u16*)(ws + 798720);
  u16* pcA    = (u16*)(ws + 1060864);
  u16* pcB    = (u16*)(ws + 1323008);
  u16* w2e    = (u16*)(ws + 1585152);         // [128][136] bf16
  u16* w2c    = (u16*)(ws + 1619968);
  float* wdwr = (float*)(ws + 1654784);       // [4][128] f32
  float* cw_t = (float*)(ws + 1656832);       // [4][256 j][256 i] f32 = 1 MB
  float* partial = (float*)(ws + 2705408);    // [4][16][8][16][128] f32 = 4 MB
  float* out  = (float*)d_out;

  hipLaunchKernelGGL(k1_ln, dim3(128), dim3(256), 0, stream,
                     h, x, lnh_w, lnh_b, lnx_w, lnx_b, hln, xln);
  hipLaunchKernelGGL(k2_pre, dim3(258), dim3(256), 0, stream,
                     hln, edg1_w, edg1_b, cor1_w, cor1_b, edg2_w, cor2_w,
                     peA, peB, pcA, pcB, w2e, w2c, wdwr);
  hipLaunchKernelGGL(k3_pair, dim3(1024), dim3(256), 0, stream,
                     x, x0, peA, peB, pcA, pcB, w2e, w2c, wdwr,
                     edg2_b, cor2_b, edgi_w, edgi_b, cor3_w, cor3_b, cw_t, partial);
  hipLaunchKernelGGL(k4_node, dim3(256), dim3(256), 0, stream,
                     hln, partial, node1_w, node1_b, node2_w, node2_b, out);
  hipLaunchKernelGGL(k5_x, dim3(256), dim3(256), 0, stream,
                     x, xln, cw_t, out);
}

// Round 3
// 292.741 us; speedup vs baseline: 1.4866x; 1.4866x over previous
//
#include <hip/hip_runtime.h>

typedef unsigned int UI;
typedef unsigned short u16;

typedef short short8 __attribute__((ext_vector_type(8)));
typedef float floatx16 __attribute__((ext_vector_type(16)));
typedef unsigned short ushort8 __attribute__((ext_vector_type(8)));

__device__ __forceinline__ float bf2f(u16 u) {
  return __uint_as_float(((UI)u) << 16);
}
__device__ __forceinline__ u16 f2bf(float x) {  // RNE
  UI u = __float_as_uint(x);
  u += 0x7fffu + ((u >> 16) & 1u);
  return (u16)(u >> 16);
}
__device__ __forceinline__ float fsigmoid(float v) {
  float e = __builtin_amdgcn_exp2f(-1.44269504089f * v);
  return __builtin_amdgcn_rcpf(1.0f + e);
}
__device__ __forceinline__ float fsilu(float v) { return v * fsigmoid(v); }

// ---------------- K1: layernorm h (128) and x (3) ----------------
__global__ __launch_bounds__(256) void k1_ln(
    const float* __restrict__ h, const float* __restrict__ x,
    const float* __restrict__ lnh_w, const float* __restrict__ lnh_b,
    const float* __restrict__ lnx_w, const float* __restrict__ lnx_b,
    float* __restrict__ hln, float* __restrict__ xln) {
  const int wv = threadIdx.x >> 6, lane = threadIdx.x & 63;
#pragma unroll 1
  for (int s = 0; s < 2; ++s) {
    const int n = blockIdx.x * 8 + wv * 2 + s;  // 128 blocks * 8 nodes
    const float* hp = h + n * 128;
    float v0 = hp[lane], v1 = hp[lane + 64];
    float sum = v0 + v1;
#pragma unroll
    for (int m = 1; m < 64; m <<= 1) sum += __shfl_xor(sum, m);
    float mean = sum * 0.0078125f;
    float d0 = v0 - mean, d1 = v1 - mean;
    float vs = d0 * d0 + d1 * d1;
#pragma unroll
    for (int m = 1; m < 64; m <<= 1) vs += __shfl_xor(vs, m);
    float rstd = __builtin_amdgcn_rcpf(__builtin_amdgcn_sqrtf(vs * 0.0078125f + 1e-5f));
    hln[n * 128 + lane]      = d0 * rstd * lnh_w[lane] + lnh_b[lane];
    hln[n * 128 + lane + 64] = d1 * rstd * lnh_w[lane + 64] + lnh_b[lane + 64];
    if (lane == 0) {
      float a = x[n * 3], b2 = x[n * 3 + 1], c = x[n * 3 + 2];
      float m3 = (a + b2 + c) * (1.f / 3.f);
      float va = (a - m3) * (a - m3) + (b2 - m3) * (b2 - m3) + (c - m3) * (c - m3);
      float rs = __builtin_amdgcn_rcpf(__builtin_amdgcn_sqrtf(va * (1.f / 3.f) + 1e-5f));
      xln[n * 3 + 0] = (a - m3) * rs * lnx_w[0] + lnx_b[0];
      xln[n * 3 + 1] = (b2 - m3) * rs * lnx_w[1] + lnx_b[1];
      xln[n * 3 + 2] = (c - m3) * rs * lnx_w[2] + lnx_b[2];
    }
  }
}

// ---------------- K2: per-node pre-GEMMs + weight repacks ----------------
__global__ __launch_bounds__(256, 2) void k2_pre(
    const float* __restrict__ hln,
    const float* __restrict__ edg1_w, const float* __restrict__ edg1_b,
    const float* __restrict__ cor1_w, const float* __restrict__ cor1_b,
    const float* __restrict__ edg2_w, const float* __restrict__ cor2_w,
    u16* __restrict__ peA, u16* __restrict__ peB,
    u16* __restrict__ pcA, u16* __restrict__ pcB,
    u16* __restrict__ w2e, u16* __restrict__ w2c,
    float* __restrict__ wdwr) {
  const int tid = threadIdx.x;
  const int bx = blockIdx.x;
  if (bx >= 256) {
    const float* src = (bx == 256) ? edg2_w : cor2_w;
    u16* dst = (bx == 256) ? w2e : w2c;
    for (int idx = tid; idx < 16384; idx += 256) {
      int f = idx >> 7, k = idx & 127;
      dst[f * 136 + k] = f2bf(src[idx]);
    }
    const float* w1 = (bx == 256) ? edg1_w : cor1_w;
    float* wvv = wdwr + ((bx == 256) ? 0 : 256);
    if (tid < 128) wvv[tid] = w1[tid * 258 + 256];           // wd (dsq col)
    else           wvv[tid] = w1[(tid - 128) * 258 + 257];   // wr (r0 col)
    return;
  }
  __shared__ __align__(16) float hl[16][132];
  const int arr = bx >> 6;
  const int nb = bx & 63;
  const int n0 = nb * 16;
  for (int idx = tid; idx < 2048; idx += 256) {
    int r = idx >> 7, k = idx & 127;
    hl[r][k] = hln[(n0 + r) * 128 + k];
  }
  __syncthreads();
  const int f = tid & 127, nh = tid >> 7;
  const float* w1 = (arr < 2) ? edg1_w : cor1_w;
  const int off = (arr & 1) ? 128 : 0;
  u16* dst = (arr == 0) ? peA : (arr == 1) ? peB : (arr == 2) ? pcA : pcB;
  float bias = 0.f;
  if (arr == 0) bias = edg1_b[f];
  if (arr == 2) bias = cor1_b[f];
  const float* wrow = w1 + f * 258 + off;
  float2 wreg[64];
#pragma unroll
  for (int t = 0; t < 64; ++t) wreg[t] = *(const float2*)(wrow + t * 2);
#pragma unroll 1
  for (int s = 0; s < 8; ++s) {
    int nl = nh * 8 + s;
    float acc = bias;
#pragma unroll
    for (int t = 0; t < 64; ++t) {
      float2 iv = *(const float2*)&hl[nl][t * 2];
      acc += wreg[t].x * iv.x + wreg[t].y * iv.y;
    }
    dst[(n0 + nl) * 128 + f] = f2bf(acc);
  }
}

// ---------------- K3: fused per-pair edge/coord MLPs ----------------
// grid 1024: path = bx>>9 (0=edge,1=cor); per wg: 16 i's x 32 j's.
// wave w: j in [w*8, w*8+8); 4 passes, ONE 32x32 m-tile (16i x 2j) each.
// __launch_bounds__(256, 1): R1/R2 both spilled (851/287 MB scratch writes)
// because (256,2)'s 256-reg budget was split 128 arch + 128 AGPR by the
// compiler and the VALU working set (~160) exceeded the 128 arch half.
// (256,1) gives the full 512-reg budget: ~160 arch + 64 acc fits w/ slack.
__global__ __launch_bounds__(256, 1) void k3_pair(
    const float* __restrict__ x, const float* __restrict__ x0,
    const u16* __restrict__ peA, const u16* __restrict__ peB,
    const u16* __restrict__ pcA, const u16* __restrict__ pcB,
    const u16* __restrict__ w2e, const u16* __restrict__ w2c,
    const float* __restrict__ wdwr,
    const float* __restrict__ b2e, const float* __restrict__ b2c,
    const float* __restrict__ edgi_w, const float* __restrict__ edgi_b,
    const float* __restrict__ cor3_w, const float* __restrict__ cor3_b,
    float* __restrict__ cw_t, float* __restrict__ partial) {
  __shared__ __align__(16) u16 sW[128 * 136];   // 34816 B, B-operand weights
  __shared__ __align__(16) u16 sA[16 * 136];    // pre_i rows (bf16)
  __shared__ __align__(16) u16 sB[32 * 136];    // pre_j rows (bf16)
  __shared__ __align__(16) float swd[128];
  __shared__ __align__(16) float swr[128];
  __shared__ float sxi[16][4], sxj[32][4], sx0i[16][4], sx0j[32][4];
  __shared__ __align__(16) float sagg[16][128]; // 8192 B

  const int tid = threadIdx.x;
  const int bx = blockIdx.x;
  const int path = bx >> 9;
  const int rem = bx & 511;
  const int b = rem >> 7;
  const int ib = (rem >> 3) & 15;
  const int jc = rem & 7;
  const int i0 = ib * 16, j0 = jc * 32;

  const u16* pA = path ? pcA : peA;
  const u16* pB = path ? pcB : peB;
  const u16* w2 = path ? w2c : w2e;
  const float* wdp = wdwr + path * 256;
  const float* b2 = path ? b2c : b2e;
  const float* w3 = path ? cor3_w : edgi_w;
  const float w3b = path ? cor3_b[0] : edgi_b[0];

  {
    const uint4* src = (const uint4*)w2;
    uint4* dst = (uint4*)sW;
    for (int d = tid; d < 2176; d += 256) dst[d] = src[d];
    const UI* sa_src = (const UI*)(pA + (b * 256 + i0) * 128);
    UI* sa_dst = (UI*)sA;
    for (int d = tid; d < 1024; d += 256) {
      int r = d >> 6, c = d & 63;
      sa_dst[r * 68 + c] = sa_src[d];
    }
    const UI* sb_src = (const UI*)(pB + (b * 256 + j0) * 128);
    UI* sb_dst = (UI*)sB;
    for (int d = tid; d < 2048; d += 256) {
      int r = d >> 6, c = d & 63;
      sb_dst[r * 68 + c] = sb_src[d];
    }
    if (tid < 128) swd[tid] = wdp[tid];
    else           swr[tid - 128] = wdp[tid];
    if (tid < 64) {
      int r = tid >> 2, d = tid & 3;
      sxi[r][d]  = (d < 3) ? x[(b * 256 + i0 + r) * 3 + d] : 0.f;
      sx0i[r][d] = (d < 3) ? x0[(b * 256 + i0 + r) * 3 + d] : 0.f;
    }
    if (tid < 128) {
      int r = tid >> 2, d = tid & 3;
      sxj[r][d]  = (d < 3) ? x[(b * 256 + j0 + r) * 3 + d] : 0.f;
      sx0j[r][d] = (d < 3) ? x0[(b * 256 + j0 + r) * 3 + d] : 0.f;
    }
    float* ag = (float*)sagg;
    for (int d = tid; d < 2048; d += 256) ag[d] = 0.f;
  }
  __syncthreads();

  const int lane = tid & 63;
  const int w = tid >> 6;
  const int h = lane >> 5;        // half-wave -> k-chunk of A/B frags
  const int c32 = lane & 31;      // MFMA m / n / col index
  const int il = c32 & 15;        // i within block (A m-row low bits)
  const int jh = (c32 >> 4) & 1;  // j lsb within m-tile

  const float wv0 = w3[c32], wv1 = w3[32 + c32], wv2 = w3[64 + c32], wv3 = w3[96 + c32];
  const float bv0 = b2[c32], bv1 = b2[32 + c32], bv2 = b2[64 + c32], bv3 = b2[96 + c32];

  float aggv[4][8];
#pragma unroll
  for (int a = 0; a < 4; ++a)
#pragma unroll
    for (int r = 0; r < 8; ++r) aggv[a][r] = 0.f;

#pragma unroll 1
  for (int g = 0; g < 4; ++g) {
    const int jl = w * 8 + g * 2 + jh;  // this lane's j within the m-tile
    float d0 = sxi[il][0] - sxj[jl][0];
    float d1 = sxi[il][1] - sxj[jl][1];
    float d2 = sxi[il][2] - sxj[jl][2];
    const float dsq = d0 * d0 + d1 * d1 + d2 * d2;
    float e0 = sx0i[il][0] - sx0j[jl][0];
    float e1 = sx0i[il][1] - sx0j[jl][1];
    float e2 = sx0i[il][2] - sx0j[jl][2];
    float q = e0 * e0 + e1 * e1 + e2 * e2;
    const float r0 = (q > 0.f) ? __builtin_amdgcn_sqrtf(q) : 0.f;

    floatx16 acc[4];
#pragma unroll
    for (int nt = 0; nt < 4; ++nt)
#pragma unroll
      for (int r = 0; r < 16; ++r) acc[nt][r] = 0.f;

    for (int ks = 0; ks < 8; ++ks) {
      const int f0 = ks * 16 + h * 8;
      union { float4 v[2]; float a[8]; } wd8, wr8;
      wd8.v[0] = *(const float4*)&swd[f0];
      wd8.v[1] = *(const float4*)&swd[f0 + 4];
      wr8.v[0] = *(const float4*)&swr[f0];
      wr8.v[1] = *(const float4*)&swr[f0 + 4];
      ushort8 a8 = *(const ushort8*)&sA[il * 136 + f0];
      ushort8 b8 = *(const ushort8*)&sB[jl * 136 + f0];
      short8 af;
#pragma unroll
      for (int e = 0; e < 8; ++e) {
        float xv = bf2f((u16)a8[e]) + bf2f((u16)b8[e]) +
                   dsq * wd8.a[e] + r0 * wr8.a[e];
        af[e] = (short)f2bf(fsilu(xv));
      }
#pragma unroll
      for (int nt = 0; nt < 4; ++nt) {
        short8 bfr = *(const short8*)&sW[(nt * 32 + c32) * 136 + f0];
        acc[nt] = __builtin_amdgcn_mfma_f32_32x32x16_bf16(af, bfr, acc[nt], 0, 0, 0);
      }
    }
    // epilogue: silu+bias, inner-product with w3, butterfly row-reduce
    float p[16];
#pragma unroll
    for (int r = 0; r < 16; ++r) {
      float s0 = fsilu(acc[0][r] + bv0); acc[0][r] = s0;
      float s1 = fsilu(acc[1][r] + bv1); acc[1][r] = s1;
      float s2 = fsilu(acc[2][r] + bv2); acc[2][r] = s2;
      float s3 = fsilu(acc[3][r] + bv3); acc[3][r] = s3;
      p[r] = s0 * wv0 + s1 * wv1 + s2 * wv2 + s3 * wv3;
    }
#pragma unroll
    for (int m = 1; m < 32; m <<= 1) {
#pragma unroll
      for (int r = 0; r < 16; ++r) p[r] += __shfl_xor(p[r], m);
    }
    if (path == 0) {
      float ev[16];
#pragma unroll
      for (int r = 0; r < 16; ++r) {
        int rb = (r & 3) + 8 * (r >> 2) + 4 * h;  // C/D row
        int ig = i0 + (rb & 15);
        int jg = j0 + w * 8 + g * 2 + (rb >> 4);
        float e = fsigmoid(p[r] + w3b);
        ev[r] = (ig == jg) ? 0.f : e;
      }
#pragma unroll
      for (int r = 0; r < 16; ++r) {
        int ra = (r & 3) + 4 * ((r >> 2) & 1);
        aggv[0][ra] += ev[r] * acc[0][r];
        aggv[1][ra] += ev[r] * acc[1][r];
        aggv[2][ra] += ev[r] * acc[2][r];
        aggv[3][ra] += ev[r] * acc[3][r];
      }
    } else {
      if (c32 < 16) {
        int r = c32;
        int rb = (r & 3) + 8 * (r >> 2) + 4 * h;
        int ig = i0 + (rb & 15);
        int jg = j0 + w * 8 + g * 2 + (rb >> 4);
        cw_t[(b * 256 + jg) * 256 + ig] = p[r] + w3b;
      }
    }
  }
  if (path == 0) {
#pragma unroll
    for (int nt = 0; nt < 4; ++nt)
#pragma unroll
      for (int ra = 0; ra < 8; ++ra) {
        int iloc = (ra & 3) + 4 * h + 8 * (ra >> 2);
        atomicAdd(&sagg[iloc][nt * 32 + c32], aggv[nt][ra]);
      }
    __syncthreads();
    float* dst = partial + ((b * 16 + ib) * 8 + jc) * 2048;
    const float* ag = (const float*)sagg;
    for (int d = tid; d < 2048; d += 256) dst[d] = ag[d];
  }
}

// ---------------- K4: node MLP + residual ----------------
__global__ __launch_bounds__(256, 2) void k4_node(
    const float* __restrict__ hln, const float* __restrict__ partial,
    const float* __restrict__ n1w, const float* __restrict__ n1b,
    const float* __restrict__ n2w, const float* __restrict__ n2b,
    float* __restrict__ out) {
  __shared__ __align__(16) float sin_[4][260];
  __shared__ __align__(16) float snu[4][132];
  const int tid = threadIdx.x;
  const int n0 = blockIdx.x * 4;
  for (int idx = tid; idx < 512; idx += 256) {
    int s = idx >> 7, k = idx & 127;
    sin_[s][k] = hln[(n0 + s) * 128 + k];
  }
  for (int idx = tid; idx < 512; idx += 256) {
    int s = idx >> 7, f = idx & 127;
    int n = n0 + s, b = n >> 8, i = n & 255;
    const float* pp = partial + ((b * 16 + (i >> 4)) * 8) * 2048 + (i & 15) * 128 + f;
    float a = 0.f;
#pragma unroll
    for (int j = 0; j < 8; ++j) a += pp[j * 2048];
    sin_[s][128 + f] = a;
  }
  __syncthreads();
  const int f = tid & 127, sh = tid >> 7;
  UI w1r[128];
#pragma unroll
  for (int t = 0; t < 128; ++t) {
    float2 wv = *(const float2*)(n1w + f * 256 + t * 2);
    w1r[t] = (UI)f2bf(wv.x) | ((UI)f2bf(wv.y) << 16);
  }
#pragma unroll 1
  for (int t2 = 0; t2 < 2; ++t2) {
    int s = sh * 2 + t2;
    float acc = n1b[f];
#pragma unroll
    for (int t = 0; t < 128; ++t) {
      UI wp = w1r[t];
      float2 iv = *(const float2*)&sin_[s][t * 2];
      acc += iv.x * bf2f((u16)(wp & 0xffffu)) + iv.y * bf2f((u16)(wp >> 16));
    }
    snu[s][f] = fsilu(acc);
  }
  __syncthreads();
  UI w2r[64];
#pragma unroll
  for (int t = 0; t < 64; ++t) {
    float2 wv = *(const float2*)(n2w + f * 128 + t * 2);
    w2r[t] = (UI)f2bf(wv.x) | ((UI)f2bf(wv.y) << 16);
  }
#pragma unroll 1
  for (int t2 = 0; t2 < 2; ++t2) {
    int s = sh * 2 + t2;
    float acc = n2b[f];
#pragma unroll
    for (int t = 0; t < 64; ++t) {
      UI wp = w2r[t];
      float2 iv = *(const float2*)&snu[s][t * 2];
      acc += iv.x * bf2f((u16)(wp & 0xffffu)) + iv.y * bf2f((u16)(wp >> 16));
    }
    out[3072 + (n0 + s) * 128 + f] = sin_[s][f] + acc;  // h_ln + node2(nu)
  }
}

// ---------------- K5: coordinate update ----------------
__global__ __launch_bounds__(256) void k5_x(
    const float* __restrict__ x, const float* __restrict__ xln,
    const float* __restrict__ cw_t, float* __restrict__ out) {
  const int wv = threadIdx.x >> 6, lane = threadIdx.x & 63;
  const int n = blockIdx.x * 4 + wv;
  const int b = n >> 8, i = n & 255;
  const float xi0 = x[n * 3 + 0], xi1 = x[n * 3 + 1], xi2 = x[n * 3 + 2];
  float s0 = 0.f, s1 = 0.f, s2 = 0.f;
#pragma unroll
  for (int t = 0; t < 4; ++t) {
    int j = t * 64 + lane;
    const float* xj = x + (b * 256 + j) * 3;
    float d0 = xi0 - xj[0], d1 = xi1 - xj[1], d2 = xi2 - xj[2];
    float q = d0 * d0 + d1 * d1 + d2 * d2;
    float r = (q > 0.f) ? __builtin_amdgcn_sqrtf(q) : 0.f;
    float cw = cw_t[(b * 256 + j) * 256 + i];
    float sc = cw * __builtin_amdgcn_rcpf(r + 1.f);
    s0 += sc * d0; s1 += sc * d1; s2 += sc * d2;
  }
#pragma unroll
  for (int m = 1; m < 64; m <<= 1) {
    s0 += __shfl_xor(s0, m);
    s1 += __shfl_xor(s1, m);
    s2 += __shfl_xor(s2, m);
  }
  if (lane == 0) {
    out[n * 3 + 0] = xln[n * 3 + 0] + s0;
    out[n * 3 + 1] = xln[n * 3 + 1] + s1;
    out[n * 3 + 2] = xln[n * 3 + 2] + s2;
  }
}

extern "C" void kernel_launch(void* const* d_in, const int* in_sizes, int n_in,
                              void* d_out, int out_size, void* d_ws, size_t ws_size,
                              hipStream_t stream) {
  (void)in_sizes; (void)n_in; (void)out_size; (void)ws_size;
  const float* x      = (const float*)d_in[0];
  const float* h      = (const float*)d_in[1];
  const float* x0     = (const float*)d_in[2];
  const float* lnh_w  = (const float*)d_in[3];
  const float* lnh_b  = (const float*)d_in[4];
  const float* lnx_w  = (const float*)d_in[5];
  const float* lnx_b  = (const float*)d_in[6];
  const float* edg1_w = (const float*)d_in[7];
  const float* edg1_b = (const float*)d_in[8];
  const float* edg2_w = (const float*)d_in[9];
  const float* edg2_b = (const float*)d_in[10];
  const float* edgi_w = (const float*)d_in[11];
  const float* edgi_b = (const float*)d_in[12];
  const float* node1_w= (const float*)d_in[13];
  const float* node1_b= (const float*)d_in[14];
  const float* node2_w= (const float*)d_in[15];
  const float* node2_b= (const float*)d_in[16];
  const float* cor1_w = (const float*)d_in[17];
  const float* cor1_b = (const float*)d_in[18];
  const float* cor2_w = (const float*)d_in[19];
  const float* cor2_b = (const float*)d_in[20];
  const float* cor3_w = (const float*)d_in[21];
  const float* cor3_b = (const float*)d_in[22];

  char* ws = (char*)d_ws;
  float* hln  = (float*)(ws);                 // 1024*128 f32 = 512 KB
  float* xln  = (float*)(ws + 524288);        // 1024*3 f32
  u16* peA    = (u16*)(ws + 536576);          // [1024][128] bf16
  u16* peB    = (u16*)(ws + 798720);
  u16* pcA    = (u16*)(ws + 1060864);
  u16* pcB    = (u16*)(ws + 1323008);
  u16* w2e    = (u16*)(ws + 1585152);         // [128][136] bf16
  u16* w2c    = (u16*)(ws + 1619968);
  float* wdwr = (float*)(ws + 1654784);       // [4][128] f32
  float* cw_t = (float*)(ws + 1656832);       // [4][256 j][256 i] f32 = 1 MB
  float* partial = (float*)(ws + 2705408);    // [4][16][8][16][128] f32 = 4 MB
  float* out  = (float*)d_out;

  hipLaunchKernelGGL(k1_ln, dim3(128), dim3(256), 0, stream,
                     h, x, lnh_w, lnh_b, lnx_w, lnx_b, hln, xln);
  hipLaunchKernelGGL(k2_pre, dim3(258), dim3(256), 0, stream,
                     hln, edg1_w, edg1_b, cor1_w, cor1_b, edg2_w, cor2_w,
                     peA, peB, pcA, pcB, w2e, w2c, wdwr);
  hipLaunchKernelGGL(k3_pair, dim3(1024), dim3(256), 0, stream,
                     x, x0, peA, peB, pcA, pcB, w2e, w2c, wdwr,
                     edg2_b, cor2_b, edgi_w, edgi_b, cor3_w, cor3_b, cw_t, partial);
  hipLaunchKernelGGL(k4_node, dim3(256), dim3(256), 0, stream,
                     hln, partial, node1_w, node1_b, node2_w, node2_b, out);
  hipLaunchKernelGGL(k5_x, dim3(256), dim3(256), 0, stream,
                     x, xln, cw_t, out);
}